// Round 7
// baseline (182.526 us; speedup 1.0000x reference)
//
#include <hip/hip_runtime.h>
#include <stdint.h>

#define B_ 2
#define S_ 2048
#define D_ 512
#define H_ 8
#define WIN_ 16
#define DIL_ 2
#define G_ 64
#define L_ (S_ - G_)   // 1984;  B_*L_ = 3968 = 31*128 exactly

typedef short bf16x8 __attribute__((ext_vector_type(8)));
typedef float f32x4 __attribute__((ext_vector_type(4)));
typedef unsigned short u16;

#define LDSW 36   // padded LDS row stride (elems): 8-way -> 2-way bank conflict

__device__ __forceinline__ float bf2f(u16 h) {
  return __uint_as_float(((uint32_t)h) << 16);
}
__device__ __forceinline__ u16 f2bf(float f) {
  uint32_t u = __float_as_uint(f);
  uint32_t r = (u + 0x7fffu + ((u >> 16) & 1u)) >> 16;
  return (u16)r;
}
__device__ __forceinline__ uint32_t pack2(float lo, float hi) {
  return (uint32_t)f2bf(lo) | ((uint32_t)f2bf(hi) << 16);
}

// ---------------- unified bf16 MFMA GEMM with fused staging ----------------
// Y = X @ W^T + bias.  W,bias fp32 (converted in staging).  X fp32 or bf16
// (X_BF16 template).  BM=128 x BN=64, BK=32, 256 thr = 4 waves (2x2),
// acc 4x2/wave.  2-phase single-barrier pipeline, padded LDS (stride 36).
struct Job {
  const void* X; const float* W; const float* bias; void* Y;
  int rpb;     // rows per batch (M = 2*rpb)
  int xoff;    // X row offset within batch
  long xbs;    // X batch stride (elems)
  int yoff;    // Y row offset within batch
  long ybs;    // Y batch stride (elems)
  int out_f32; // Y dtype: 1=f32, 0=bf16
};
struct GemmLaunch { int start[6]; Job job[6]; };

template <int X_BF16>
__global__ __launch_bounds__(256) void gemm_kernel(GemmLaunch a) {
  // XCD-bijective swizzle (host guarantees gridDim.x % 8 == 0)
  int bid = (int)blockIdx.x;
  bid = (bid & 7) * ((int)gridDim.x >> 3) + (bid >> 3);

  int j = 0;
#pragma unroll
  for (int i = 1; i < 6; ++i) j = (bid >= a.start[i]) ? i : j;
  const Job jb = a.job[j];
  bid -= a.start[j];
  const int tm = bid >> 3, tn = bid & 7;   // ntiles_n = 512/64 = 8
  const int row0 = tm * 128, n0 = tn * 64;

  __shared__ __align__(16) u16 As[2][128 * LDSW];
  __shared__ __align__(16) u16 Bs[2][64 * LDSW];

  const int tid = threadIdx.x, lane = tid & 63, w = tid >> 6;
  const int wm = w >> 1, wn = w & 1;

  const int rs = tid >> 2;          // 0..63
  const int kq = (tid & 3) * 8;

  const int r0 = row0 + rs,      b0 = r0 >= jb.rpb;
  const int r1 = row0 + 64 + rs, b1 = r1 >= jb.rpb;
  const size_t xi0 = (size_t)(b0 ? jb.xbs : 0) +
                     (size_t)(jb.xoff + r0 - (b0 ? jb.rpb : 0)) * 512 + kq;
  const size_t xi1 = (size_t)(b1 ? jb.xbs : 0) +
                     (size_t)(jb.xoff + r1 - (b1 ? jb.rpb : 0)) * 512 + kq;
  const float* wb0 = jb.W + (size_t)(n0 + rs) * 512 + kq;

  f32x4 acc[4][2];
#pragma unroll
  for (int i = 0; i < 4; ++i)
#pragma unroll
    for (int k = 0; k < 2; ++k) acc[i][k] = (f32x4){0.f, 0.f, 0.f, 0.f};

  auto cvt_store_f32 = [&](const float* src, u16* dst) {
    float4 lo = *(const float4*)src;
    float4 hi = *(const float4*)(src + 4);
    int4 p;
    p.x = (int)pack2(lo.x, lo.y);
    p.y = (int)pack2(lo.z, lo.w);
    p.z = (int)pack2(hi.x, hi.y);
    p.w = (int)pack2(hi.z, hi.w);
    *(int4*)dst = p;
  };
  auto stage = [&](int buf, int kof) {
    if (X_BF16) {
      const u16* xb = (const u16*)jb.X;
      *(int4*)&As[buf][rs * LDSW + kq]        = *(const int4*)&xb[xi0 + kof];
      *(int4*)&As[buf][(64 + rs) * LDSW + kq] = *(const int4*)&xb[xi1 + kof];
    } else {
      const float* xf = (const float*)jb.X;
      cvt_store_f32(xf + xi0 + kof, &As[buf][rs * LDSW + kq]);
      cvt_store_f32(xf + xi1 + kof, &As[buf][(64 + rs) * LDSW + kq]);
    }
    cvt_store_f32(wb0 + kof, &Bs[buf][rs * LDSW + kq]);
  };
  auto compute = [&](int buf) {
    bf16x8 af[4], bfv[2];
#pragma unroll
    for (int fm = 0; fm < 4; ++fm)
      af[fm] = *(const bf16x8*)&As[buf][(wm * 64 + fm * 16 + (lane & 15)) * LDSW + 8 * (lane >> 4)];
#pragma unroll
    for (int fn = 0; fn < 2; ++fn)
      bfv[fn] = *(const bf16x8*)&Bs[buf][(wn * 32 + fn * 16 + (lane & 15)) * LDSW + 8 * (lane >> 4)];
#pragma unroll
    for (int fm = 0; fm < 4; ++fm)
#pragma unroll
      for (int fn = 0; fn < 2; ++fn)
        acc[fm][fn] = __builtin_amdgcn_mfma_f32_16x16x32_bf16(af[fm], bfv[fn], acc[fm][fn], 0, 0, 0);
  };

  stage(0, 0);
  __syncthreads();
  int cur = 0;
  for (int kt = 0; kt < 15; ++kt) {
    stage(cur ^ 1, (kt + 1) * 32);  // next tile's loads+cvt fly during compute
    compute(cur);
    __syncthreads();
    cur ^= 1;
  }
  compute(cur);

#pragma unroll
  for (int fm = 0; fm < 4; ++fm) {
#pragma unroll
    for (int fn = 0; fn < 2; ++fn) {
#pragma unroll
      for (int r = 0; r < 4; ++r) {
        const int row = row0 + wm * 64 + fm * 16 + (lane >> 4) * 4 + r;
        const int col = n0 + wn * 32 + fn * 16 + (lane & 15);
        const int b = row >= jb.rpb;
        const int rr = row - (b ? jb.rpb : 0);
        const size_t yi = (size_t)(b ? jb.ybs : 0) + (size_t)(jb.yoff + rr) * 512 + col;
        const float v = acc[fm][fn][r] + jb.bias[col];
        if (jb.out_f32) ((float*)jb.Y)[yi] = v;
        else            ((u16*)jb.Y)[yi]   = f2bf(v);
      }
    }
  }
}

// ---------------- fused attention (local windowed + global) ----------------
__global__ __launch_bounds__(256) void attn_kernel(const u16* qp, const u16* kp,
                                                   const u16* vp, u16* ob,
                                                   const u16* qgp, const u16* kgp,
                                                   const u16* vgp, u16* ogp) {
  const int lane = threadIdx.x & 63;
  int bid = (int)blockIdx.x;
  const int nbl = (B_ * L_) / 4;    // 992 = 8*124
  if (bid < nbl) bid = (bid & 7) * (nbl >> 3) + (bid >> 3);
  const int wid = bid * 4 + (threadIdx.x >> 6);

  if (wid < B_ * L_) {
    const int l = wid % L_;
    const int brow = wid - l;   // batch base row
    float q[8];
    {
      bf16x8 qv = *(const bf16x8*)&qp[(size_t)wid * 512 + lane * 8];
#pragma unroll
      for (int e = 0; e < 8; ++e) q[e] = bf2f((u16)qv[e]);
    }
    float s[WIN_];
#pragma unroll
    for (int w2 = 0; w2 < WIN_; ++w2) {
      int ki = l + DIL_ * w2 - WIN_;
      ki = ki < 0 ? 0 : (ki > L_ - 1 ? L_ - 1 : ki);
      bf16x8 kv = *(const bf16x8*)&kp[(size_t)(brow + ki) * 512 + lane * 8];
      float p = 0.f;
#pragma unroll
      for (int e = 0; e < 8; ++e) p = fmaf(q[e], bf2f((u16)kv[e]), p);
      p += __shfl_xor(p, 1); p += __shfl_xor(p, 2); p += __shfl_xor(p, 4);
      s[w2] = p * 0.125f;
    }
    float m = s[0];
#pragma unroll
    for (int w2 = 1; w2 < WIN_; ++w2) m = fmaxf(m, s[w2]);
    float sum = 0.f;
#pragma unroll
    for (int w2 = 0; w2 < WIN_; ++w2) { s[w2] = __expf(s[w2] - m); sum += s[w2]; }
    const float inv = 1.0f / sum;
    float acc[8] = {0.f};
#pragma unroll
    for (int w2 = 0; w2 < WIN_; ++w2) {
      int ki = l + DIL_ * w2 - WIN_;
      ki = ki < 0 ? 0 : (ki > L_ - 1 ? L_ - 1 : ki);
      bf16x8 vv = *(const bf16x8*)&vp[(size_t)(brow + ki) * 512 + lane * 8];
#pragma unroll
      for (int e = 0; e < 8; ++e) acc[e] = fmaf(s[w2], bf2f((u16)vv[e]), acc[e]);
    }
    bf16x8 o8;
#pragma unroll
    for (int e = 0; e < 8; ++e) o8[e] = (short)f2bf(acc[e] * inv);
    *(bf16x8*)&ob[(size_t)wid * 512 + lane * 8] = o8;
  } else {
    const int g = wid - B_ * L_;         // 0..127
    const int base = (g >> 6) * 64;      // b*64
    const int qi = g & 63;
    float q[8];
    {
      bf16x8 qv = *(const bf16x8*)&qgp[(size_t)(base + qi) * 512 + lane * 8];
#pragma unroll
      for (int e = 0; e < 8; ++e) q[e] = bf2f((u16)qv[e]);
    }
    float m = -1e30f, sum = 0.f, acc[8] = {0.f};
    for (int j2 = 0; j2 < 64; ++j2) {
      bf16x8 kv = *(const bf16x8*)&kgp[(size_t)(base + j2) * 512 + lane * 8];
      float p = 0.f;
#pragma unroll
      for (int e = 0; e < 8; ++e) p = fmaf(q[e], bf2f((u16)kv[e]), p);
      p += __shfl_xor(p, 1); p += __shfl_xor(p, 2); p += __shfl_xor(p, 4);
      p *= 0.125f;
      const float mn = fmaxf(m, p);
      const float c  = __expf(m - mn);
      const float pe = __expf(p - mn);
      sum = sum * c + pe;
      m = mn;
      bf16x8 vv = *(const bf16x8*)&vgp[(size_t)(base + j2) * 512 + lane * 8];
#pragma unroll
      for (int e = 0; e < 8; ++e) acc[e] = acc[e] * c + pe * bf2f((u16)vv[e]);
    }
    const float inv = 1.0f / sum;
    bf16x8 o8;
#pragma unroll
    for (int e = 0; e < 8; ++e) o8[e] = (short)f2bf(acc[e] * inv);
    *(bf16x8*)&ogp[(size_t)(base + qi) * 512 + lane * 8] = o8;
  }
}

// ---------------- host ----------------
extern "C" void kernel_launch(void* const* d_in, const int* in_sizes, int n_in,
                              void* d_out, int out_size, void* d_ws, size_t ws_size,
                              hipStream_t stream) {
  const float* query   = (const float*)d_in[0];
  const float* key     = (const float*)d_in[1];
  const float* value   = (const float*)d_in[2];
  const float* wq      = (const float*)d_in[3];
  const float* bq      = (const float*)d_in[4];
  const float* wk      = (const float*)d_in[5];
  const float* bk      = (const float*)d_in[6];
  const float* wv      = (const float*)d_in[7];
  const float* bv      = (const float*)d_in[8];
  const float* wo      = (const float*)d_in[9];
  const float* bo      = (const float*)d_in[10];
  const float* g_in_w  = (const float*)d_in[11];
  const float* g_in_b  = (const float*)d_in[12];
  const float* g_out_w = (const float*)d_in[13];
  const float* g_out_b = (const float*)d_in[14];
  float* out = (float*)d_out;

  u16* w16 = (u16*)d_ws;
  const size_t PSZ = (size_t)B_ * L_ * D_;   // 2031616
  const size_t GSZ = (size_t)B_ * G_ * D_;   // 65536

  u16* qp  = w16;        u16* kp  = qp + PSZ;   u16* vp  = kp + PSZ;
  u16* ob  = vp + PSZ;
  u16* qgp = ob + PSZ;   u16* kgp = qgp + GSZ;  u16* vgp = kgp + GSZ;
  u16* ogp = vgp + GSZ;

  const long XBS = (long)S_ * D_;   // 1048576
  const long PBS = (long)L_ * D_;   // 1015808
  const long GBS = (long)G_ * D_;   // 32768

  // 1) input projections (fp32 X): 3 local (248 blocks) + 3 global (8) = 768
  GemmLaunch gi;
  gi.start[0] = 0; gi.start[1] = 248; gi.start[2] = 496;
  gi.start[3] = 744; gi.start[4] = 752; gi.start[5] = 760;
  gi.job[0] = {query, wq, bq, qp, L_, G_, XBS, 0, PBS, 0};
  gi.job[1] = {key,   wk, bk, kp, L_, G_, XBS, 0, PBS, 0};
  gi.job[2] = {value, wv, bv, vp, L_, G_, XBS, 0, PBS, 0};
  gi.job[3] = {query, g_in_w,             g_in_b,          qgp, G_, 0, XBS, 0, GBS, 0};
  gi.job[4] = {key,   g_in_w + 512 * D_,  g_in_b + D_,     kgp, G_, 0, XBS, 0, GBS, 0};
  gi.job[5] = {value, g_in_w + 1024 * D_, g_in_b + 2 * D_, vgp, G_, 0, XBS, 0, GBS, 0};
  hipLaunchKernelGGL(gemm_kernel<0>, dim3(768), dim3(256), 0, stream, gi);

  // 2) fused attention: 992 local blocks + 32 global blocks
  hipLaunchKernelGGL(attn_kernel, dim3((B_ * L_ + 128) / 4), dim3(256), 0, stream,
                     qp, kp, vp, ob, qgp, kgp, vgp, ogp);

  // 3) output projections (bf16 X, fp32 Y): 248 + 8 = 256 blocks
  GemmLaunch go;
  go.start[0] = 0; go.start[1] = 248;
  go.start[2] = go.start[3] = go.start[4] = go.start[5] = 0x7fffffff;
  go.job[0] = {ob,  wo,      bo,      out, L_, 0, PBS, G_, XBS, 1};
  go.job[1] = {ogp, g_out_w, g_out_b, out, G_, 0, GBS, 0,  XBS, 1};
  go.job[2] = go.job[1]; go.job[3] = go.job[1]; go.job[4] = go.job[1]; go.job[5] = go.job[1];
  hipLaunchKernelGGL(gemm_kernel<1>, dim3(256), dim3(256), 0, stream, go);
}

// Round 11
// 162.218 us; speedup vs baseline: 1.1252x; 1.1252x over previous
//
#include <hip/hip_runtime.h>
#include <stdint.h>

#define B_ 2
#define S_ 2048
#define D_ 512
#define H_ 8
#define WIN_ 16
#define DIL_ 2
#define G_ 64
#define L_ (S_ - G_)   // 1984;  B_*L_ = 3968 = 31*128 exactly

typedef short bf16x8 __attribute__((ext_vector_type(8)));
typedef float f32x4 __attribute__((ext_vector_type(4)));
typedef unsigned short u16;

// padded LDS row stride (elems). 40*2=80B: 16B-aligned (b128 ok) and start
// banks r*20%32 cycle through 8 groups -> ~2-way conflict (free, m136).
#define LDSW 40

__device__ __forceinline__ float bf2f(u16 h) {
  return __uint_as_float(((uint32_t)h) << 16);
}
__device__ __forceinline__ u16 f2bf(float f) {
  uint32_t u = __float_as_uint(f);
  uint32_t r = (u + 0x7fffu + ((u >> 16) & 1u)) >> 16;
  return (u16)r;
}
__device__ __forceinline__ uint32_t pack2(float lo, float hi) {
  return (uint32_t)f2bf(lo) | ((uint32_t)f2bf(hi) << 16);
}

// ---------------- unified bf16 MFMA GEMM with fused staging ----------------
// Y = X @ W^T + bias.  W,bias fp32 (converted during staging).  X fp32 or
// bf16 (template).  BM=128 x BN=64, BK=32, 256 thr = 4 waves (2x2),
// acc 4x2/wave.  Depth-2 register prefetch (T14 issue-early/write-late):
//   issue loads(t+2) -> regs ; MFMA(t) ; cvt+ds_write(t+1) [auto vmcnt(6)] ;
//   barrier.  One barrier per K-step, no vmcnt(0) drain in the loop.
struct Job {
  const void* X; const float* W; const float* bias; void* Y;
  int rpb;     // rows per batch (M = 2*rpb)
  int xoff;    // X row offset within batch
  long xbs;    // X batch stride (elems)
  int yoff;    // Y row offset within batch
  long ybs;    // Y batch stride (elems)
  int out_f32; // Y dtype: 1=f32, 0=bf16
};
struct GemmLaunch { int start[6]; Job job[6]; };

template <int X_BF16>
__global__ __launch_bounds__(256) void gemm_kernel(GemmLaunch a) {
  // XCD-bijective swizzle (host guarantees gridDim.x % 8 == 0)
  int bid = (int)blockIdx.x;
  bid = (bid & 7) * ((int)gridDim.x >> 3) + (bid >> 3);

  int j = 0;
#pragma unroll
  for (int i = 1; i < 6; ++i) j = (bid >= a.start[i]) ? i : j;
  const Job jb = a.job[j];
  bid -= a.start[j];
  const int tm = bid >> 3, tn = bid & 7;   // ntiles_n = 512/64 = 8
  const int row0 = tm * 128, n0 = tn * 64;

  __shared__ __align__(16) u16 As[2][128 * LDSW];  // 2 x 10 KB
  __shared__ __align__(16) u16 Bs[2][64 * LDSW];   // 2 x 5 KB

  const int tid = threadIdx.x, lane = tid & 63, w = tid >> 6;
  const int wm = w >> 1, wn = w & 1;

  const int rs = tid >> 2;          // 0..63
  const int kq = (tid & 3) * 8;

  const int r0 = row0 + rs,      b0 = r0 >= jb.rpb;
  const int r1 = row0 + 64 + rs, b1 = r1 >= jb.rpb;
  const size_t xi0 = (size_t)(b0 ? jb.xbs : 0) +
                     (size_t)(jb.xoff + r0 - (b0 ? jb.rpb : 0)) * 512 + kq;
  const size_t xi1 = (size_t)(b1 ? jb.xbs : 0) +
                     (size_t)(jb.xoff + r1 - (b1 ? jb.rpb : 0)) * 512 + kq;
  const float* wb0 = jb.W + (size_t)(n0 + rs) * 512 + kq;

  f32x4 acc[4][2];
#pragma unroll
  for (int i = 0; i < 4; ++i)
#pragma unroll
    for (int k = 0; k < 2; ++k) acc[i][k] = (f32x4){0.f, 0.f, 0.f, 0.f};

  // depth-2 register staging: two NAMED batches (rule #20: no runtime index)
  f32x4 Aa0, Aa1, Aa2, Aa3, Aw0, Aw1;   // batch A (fp32-X variant)
  f32x4 Ba0, Ba1, Ba2, Ba3, Bw0, Bw1;   // batch B
  int4  Ax0, Ax1, Bx0, Bx1;             // bf16-X variant

  auto issueA = [&](int kof) {
    if constexpr (X_BF16) {
      const u16* xb = (const u16*)jb.X;
      Ax0 = *(const int4*)&xb[xi0 + kof];
      Ax1 = *(const int4*)&xb[xi1 + kof];
    } else {
      const float* xf = (const float*)jb.X;
      Aa0 = *(const f32x4*)(xf + xi0 + kof);
      Aa1 = *(const f32x4*)(xf + xi0 + kof + 4);
      Aa2 = *(const f32x4*)(xf + xi1 + kof);
      Aa3 = *(const f32x4*)(xf + xi1 + kof + 4);
    }
    Aw0 = *(const f32x4*)(wb0 + kof);
    Aw1 = *(const f32x4*)(wb0 + kof + 4);
  };
  auto issueB = [&](int kof) {
    if constexpr (X_BF16) {
      const u16* xb = (const u16*)jb.X;
      Bx0 = *(const int4*)&xb[xi0 + kof];
      Bx1 = *(const int4*)&xb[xi1 + kof];
    } else {
      const float* xf = (const float*)jb.X;
      Ba0 = *(const f32x4*)(xf + xi0 + kof);
      Ba1 = *(const f32x4*)(xf + xi0 + kof + 4);
      Ba2 = *(const f32x4*)(xf + xi1 + kof);
      Ba3 = *(const f32x4*)(xf + xi1 + kof + 4);
    }
    Bw0 = *(const f32x4*)(wb0 + kof);
    Bw1 = *(const f32x4*)(wb0 + kof + 4);
  };
  auto writeA = [&](int buf) {
    if constexpr (X_BF16) {
      *(int4*)&As[buf][rs * LDSW + kq]        = Ax0;
      *(int4*)&As[buf][(64 + rs) * LDSW + kq] = Ax1;
    } else {
      int4 p;
      p.x = (int)pack2(Aa0[0], Aa0[1]); p.y = (int)pack2(Aa0[2], Aa0[3]);
      p.z = (int)pack2(Aa1[0], Aa1[1]); p.w = (int)pack2(Aa1[2], Aa1[3]);
      *(int4*)&As[buf][rs * LDSW + kq] = p;
      p.x = (int)pack2(Aa2[0], Aa2[1]); p.y = (int)pack2(Aa2[2], Aa2[3]);
      p.z = (int)pack2(Aa3[0], Aa3[1]); p.w = (int)pack2(Aa3[2], Aa3[3]);
      *(int4*)&As[buf][(64 + rs) * LDSW + kq] = p;
    }
    int4 pw;
    pw.x = (int)pack2(Aw0[0], Aw0[1]); pw.y = (int)pack2(Aw0[2], Aw0[3]);
    pw.z = (int)pack2(Aw1[0], Aw1[1]); pw.w = (int)pack2(Aw1[2], Aw1[3]);
    *(int4*)&Bs[buf][rs * LDSW + kq] = pw;
  };
  auto writeB = [&](int buf) {
    if constexpr (X_BF16) {
      *(int4*)&As[buf][rs * LDSW + kq]        = Bx0;
      *(int4*)&As[buf][(64 + rs) * LDSW + kq] = Bx1;
    } else {
      int4 p;
      p.x = (int)pack2(Ba0[0], Ba0[1]); p.y = (int)pack2(Ba0[2], Ba0[3]);
      p.z = (int)pack2(Ba1[0], Ba1[1]); p.w = (int)pack2(Ba1[2], Ba1[3]);
      *(int4*)&As[buf][rs * LDSW + kq] = p;
      p.x = (int)pack2(Ba2[0], Ba2[1]); p.y = (int)pack2(Ba2[2], Ba2[3]);
      p.z = (int)pack2(Ba3[0], Ba3[1]); p.w = (int)pack2(Ba3[2], Ba3[3]);
      *(int4*)&As[buf][(64 + rs) * LDSW + kq] = p;
    }
    int4 pw;
    pw.x = (int)pack2(Bw0[0], Bw0[1]); pw.y = (int)pack2(Bw0[2], Bw0[3]);
    pw.z = (int)pack2(Bw1[0], Bw1[1]); pw.w = (int)pack2(Bw1[2], Bw1[3]);
    *(int4*)&Bs[buf][rs * LDSW + kq] = pw;
  };
  auto compute = [&](int buf) {
    bf16x8 af[4], bfv[2];
#pragma unroll
    for (int fm = 0; fm < 4; ++fm)
      af[fm] = *(const bf16x8*)&As[buf][(wm * 64 + fm * 16 + (lane & 15)) * LDSW + 8 * (lane >> 4)];
#pragma unroll
    for (int fn = 0; fn < 2; ++fn)
      bfv[fn] = *(const bf16x8*)&Bs[buf][(wn * 32 + fn * 16 + (lane & 15)) * LDSW + 8 * (lane >> 4)];
#pragma unroll
    for (int fm = 0; fm < 4; ++fm)
#pragma unroll
      for (int fn = 0; fn < 2; ++fn)
        acc[fm][fn] = __builtin_amdgcn_mfma_f32_16x16x32_bf16(af[fm], bfv[fn], acc[fm][fn], 0, 0, 0);
  };

  // tiles 0..15 (K=512, BK=32).  Invariant at loop top (t even):
  //   LDS[0]=tile t ready, regs B = tile t+1 in flight, regs A free.
  issueA(0);
  issueB(32);
  writeA(0);          // waits only batch-A loads (vmcnt(6))
  __syncthreads();
  for (int t = 0; t < 14; t += 2) {
    issueA((t + 2) * 32);
    compute(0);       // tile t   (B-batch loads in flight underneath)
    writeB(1);        // tile t+1 (auto vmcnt(6): A-batch still outstanding)
    __syncthreads();
    issueB((t + 3) * 32);
    compute(1);       // tile t+1
    writeA(0);        // tile t+2
    __syncthreads();
  }
  compute(0);         // tile 14
  writeB(1);          // tile 15
  __syncthreads();
  compute(1);         // tile 15

#pragma unroll
  for (int fm = 0; fm < 4; ++fm) {
#pragma unroll
    for (int fn = 0; fn < 2; ++fn) {
#pragma unroll
      for (int r = 0; r < 4; ++r) {
        const int row = row0 + wm * 64 + fm * 16 + (lane >> 4) * 4 + r;
        const int col = n0 + wn * 32 + fn * 16 + (lane & 15);
        const int b = row >= jb.rpb;
        const int rr = row - (b ? jb.rpb : 0);
        const size_t yi = (size_t)(b ? jb.ybs : 0) + (size_t)(jb.yoff + rr) * 512 + col;
        const float v = acc[fm][fn][r] + jb.bias[col];
        if (jb.out_f32) ((float*)jb.Y)[yi] = v;
        else            ((u16*)jb.Y)[yi]   = f2bf(v);
      }
    }
  }
}

// ---------------- fused attention (local windowed + global) ----------------
__global__ __launch_bounds__(256) void attn_kernel(const u16* qp, const u16* kp,
                                                   const u16* vp, u16* ob,
                                                   const u16* qgp, const u16* kgp,
                                                   const u16* vgp, u16* ogp) {
  const int lane = threadIdx.x & 63;
  int bid = (int)blockIdx.x;
  const int nbl = (B_ * L_) / 4;    // 992 = 8*124
  if (bid < nbl) bid = (bid & 7) * (nbl >> 3) + (bid >> 3);
  const int wid = bid * 4 + (threadIdx.x >> 6);

  if (wid < B_ * L_) {
    const int l = wid % L_;
    const int brow = wid - l;   // batch base row
    float q[8];
    {
      bf16x8 qv = *(const bf16x8*)&qp[(size_t)wid * 512 + lane * 8];
#pragma unroll
      for (int e = 0; e < 8; ++e) q[e] = bf2f((u16)qv[e]);
    }
    float s[WIN_];
#pragma unroll
    for (int w2 = 0; w2 < WIN_; ++w2) {
      int ki = l + DIL_ * w2 - WIN_;
      ki = ki < 0 ? 0 : (ki > L_ - 1 ? L_ - 1 : ki);
      bf16x8 kv = *(const bf16x8*)&kp[(size_t)(brow + ki) * 512 + lane * 8];
      float p = 0.f;
#pragma unroll
      for (int e = 0; e < 8; ++e) p = fmaf(q[e], bf2f((u16)kv[e]), p);
      p += __shfl_xor(p, 1); p += __shfl_xor(p, 2); p += __shfl_xor(p, 4);
      s[w2] = p * 0.125f;
    }
    float m = s[0];
#pragma unroll
    for (int w2 = 1; w2 < WIN_; ++w2) m = fmaxf(m, s[w2]);
    float sum = 0.f;
#pragma unroll
    for (int w2 = 0; w2 < WIN_; ++w2) { s[w2] = __expf(s[w2] - m); sum += s[w2]; }
    const float inv = 1.0f / sum;
    float acc[8] = {0.f};
#pragma unroll
    for (int w2 = 0; w2 < WIN_; ++w2) {
      int ki = l + DIL_ * w2 - WIN_;
      ki = ki < 0 ? 0 : (ki > L_ - 1 ? L_ - 1 : ki);
      bf16x8 vv = *(const bf16x8*)&vp[(size_t)(brow + ki) * 512 + lane * 8];
#pragma unroll
      for (int e = 0; e < 8; ++e) acc[e] = fmaf(s[w2], bf2f((u16)vv[e]), acc[e]);
    }
    bf16x8 o8;
#pragma unroll
    for (int e = 0; e < 8; ++e) o8[e] = (short)f2bf(acc[e] * inv);
    *(bf16x8*)&ob[(size_t)wid * 512 + lane * 8] = o8;
  } else {
    const int g = wid - B_ * L_;         // 0..127
    const int base = (g >> 6) * 64;      // b*64
    const int qi = g & 63;
    float q[8];
    {
      bf16x8 qv = *(const bf16x8*)&qgp[(size_t)(base + qi) * 512 + lane * 8];
#pragma unroll
      for (int e = 0; e < 8; ++e) q[e] = bf2f((u16)qv[e]);
    }
    float m = -1e30f, sum = 0.f, acc[8] = {0.f};
    for (int j2 = 0; j2 < 64; ++j2) {
      bf16x8 kv = *(const bf16x8*)&kgp[(size_t)(base + j2) * 512 + lane * 8];
      float p = 0.f;
#pragma unroll
      for (int e = 0; e < 8; ++e) p = fmaf(q[e], bf2f((u16)kv[e]), p);
      p += __shfl_xor(p, 1); p += __shfl_xor(p, 2); p += __shfl_xor(p, 4);
      p *= 0.125f;
      const float mn = fmaxf(m, p);
      const float c  = __expf(m - mn);
      const float pe = __expf(p - mn);
      sum = sum * c + pe;
      m = mn;
      bf16x8 vv = *(const bf16x8*)&vgp[(size_t)(base + j2) * 512 + lane * 8];
#pragma unroll
      for (int e = 0; e < 8; ++e) acc[e] = acc[e] * c + pe * bf2f((u16)vv[e]);
    }
    const float inv = 1.0f / sum;
    bf16x8 o8;
#pragma unroll
    for (int e = 0; e < 8; ++e) o8[e] = (short)f2bf(acc[e] * inv);
    *(bf16x8*)&ogp[(size_t)(base + qi) * 512 + lane * 8] = o8;
  }
}

// ---------------- host ----------------
extern "C" void kernel_launch(void* const* d_in, const int* in_sizes, int n_in,
                              void* d_out, int out_size, void* d_ws, size_t ws_size,
                              hipStream_t stream) {
  const float* query   = (const float*)d_in[0];
  const float* key     = (const float*)d_in[1];
  const float* value   = (const float*)d_in[2];
  const float* wq      = (const float*)d_in[3];
  const float* bq      = (const float*)d_in[4];
  const float* wk      = (const float*)d_in[5];
  const float* bk      = (const float*)d_in[6];
  const float* wv      = (const float*)d_in[7];
  const float* bv      = (const float*)d_in[8];
  const float* wo      = (const float*)d_in[9];
  const float* bo      = (const float*)d_in[10];
  const float* g_in_w  = (const float*)d_in[11];
  const float* g_in_b  = (const float*)d_in[12];
  const float* g_out_w = (const float*)d_in[13];
  const float* g_out_b = (const float*)d_in[14];
  float* out = (float*)d_out;

  u16* w16 = (u16*)d_ws;
  const size_t PSZ = (size_t)B_ * L_ * D_;   // 2031616
  const size_t GSZ = (size_t)B_ * G_ * D_;   // 65536

  u16* qp  = w16;        u16* kp  = qp + PSZ;   u16* vp  = kp + PSZ;
  u16* ob  = vp + PSZ;
  u16* qgp = ob + PSZ;   u16* kgp = qgp + GSZ;  u16* vgp = kgp + GSZ;
  u16* ogp = vgp + GSZ;

  const long XBS = (long)S_ * D_;   // 1048576
  const long PBS = (long)L_ * D_;   // 1015808
  const long GBS = (long)G_ * D_;   // 32768

  // 1) input projections (fp32 X): 3 local (248 blocks) + 3 global (8) = 768
  GemmLaunch gi;
  gi.start[0] = 0; gi.start[1] = 248; gi.start[2] = 496;
  gi.start[3] = 744; gi.start[4] = 752; gi.start[5] = 760;
  gi.job[0] = {query, wq, bq, qp, L_, G_, XBS, 0, PBS, 0};
  gi.job[1] = {key,   wk, bk, kp, L_, G_, XBS, 0, PBS, 0};
  gi.job[2] = {value, wv, bv, vp, L_, G_, XBS, 0, PBS, 0};
  gi.job[3] = {query, g_in_w,             g_in_b,          qgp, G_, 0, XBS, 0, GBS, 0};
  gi.job[4] = {key,   g_in_w + 512 * D_,  g_in_b + D_,     kgp, G_, 0, XBS, 0, GBS, 0};
  gi.job[5] = {value, g_in_w + 1024 * D_, g_in_b + 2 * D_, vgp, G_, 0, XBS, 0, GBS, 0};
  hipLaunchKernelGGL(gemm_kernel<0>, dim3(768), dim3(256), 0, stream, gi);

  // 2) fused attention: 992 local blocks + 32 global blocks
  hipLaunchKernelGGL(attn_kernel, dim3((B_ * L_ + 128) / 4), dim3(256), 0, stream,
                     qp, kp, vp, ob, qgp, kgp, vgp, ogp);

  // 3) output projections (bf16 X, fp32 Y): 248 + 8 = 256 blocks
  GemmLaunch go;
  go.start[0] = 0; go.start[1] = 248;
  go.start[2] = go.start[3] = go.start[4] = go.start[5] = 0x7fffffff;
  go.job[0] = {ob,  wo,      bo,      out, L_, 0, PBS, G_, XBS, 1};
  go.job[1] = {ogp, g_out_w, g_out_b, out, G_, 0, GBS, 0,  XBS, 1};
  go.job[2] = go.job[1]; go.job[3] = go.job[1]; go.job[4] = go.job[1]; go.job[5] = go.job[1];
  hipLaunchKernelGGL(gemm_kernel<1>, dim3(256), dim3(256), 0, stream, go);
}